// Round 3
// baseline (315.316 us; speedup 1.0000x reference)
//
#include <hip/hip_runtime.h>

// SpatialTransformer3D: B=2, H=W=D=128, C=4.
// out[b,i,j,k,:] = trilinear sample of image[b] at coords = t * grid.
// Latency-bound random-gather kernel: process 2 voxels/thread, phase-split so
// all 16 corner loads are in flight together; nt hints keep L2 for the image.

typedef float f4 __attribute__((ext_vector_type(4)));

__global__ __launch_bounds__(256) void st3d_kernel(
    const float* __restrict__ img,     // (B,128,128,128,4)
    const float* __restrict__ trans,   // (B,128,128,128,3)
    f4* __restrict__ out,              // (B,128,128,128,4) as float4
    int N)                             // B*128^3
{
    constexpr int V = 2;
    int base = blockIdx.x * (256 * V) + threadIdx.x;

    const f4* img4 = (const f4*)img;

    int   idxv[V];
    int   A0[V], A1[V], A2[V], A3[V];   // f4 index of (y0,x0,z0),(y1,x0,z0),(y0,x1,z0),(y1,x1,z0)
    int   dzi[V];                       // z1 - z0 (0 or 1)
    float w000[V], w100[V], w010[V], w110[V];
    float w001[V], w101[V], w011[V], w111[V];

    // ---- Phase 1: trans loads + address/weight math ----
#pragma unroll
    for (int v = 0; v < V; ++v) {
        int idx = base + v * 256;
        idxv[v] = idx;
        if (idx >= N) idx = 0;          // safe dummy

        int k = idx & 127;
        int j = (idx >> 7) & 127;
        int i = (idx >> 14) & 127;
        int b = idx >> 21;

        const float step = 2.0f / 127.0f;
        float gx = -1.0f + step * (float)j;
        float gy = -1.0f + step * (float)i;
        float gz = -1.0f + step * (float)k;

        const float* t = trans + (size_t)idx * 3;
        float tx = __builtin_nontemporal_load(t + 0);
        float ty = __builtin_nontemporal_load(t + 1);
        float tz = __builtin_nontemporal_load(t + 2);

        float x = (tx * gx + 1.0f) * 64.0f;
        float y = (ty * gy + 1.0f) * 64.0f;
        float z = (tz * gz + 1.0f) * 64.0f;

        int x0 = (int)floorf(x);
        int y0 = (int)floorf(y);
        int z0 = (int)floorf(z);
        int x1 = min(max(x0 + 1, 0), 127);
        int y1 = min(max(y0 + 1, 0), 127);
        int z1 = min(max(z0 + 1, 0), 127);
        x0 = min(max(x0, 0), 127);
        y0 = min(max(y0, 0), 127);
        z0 = min(max(z0, 0), 127);

        float dx = (float)x1 - x;
        float dy = (float)y1 - y;
        float dz = (float)z1 - z;
        float ex = 1.0f - dx;
        float ey = 1.0f - dy;
        float ez = 1.0f - dz;

        int bb  = b << 21;
        int ry0 = bb + (y0 << 14);
        int ry1 = bb + (y1 << 14);
        int cx0 = x0 << 7;
        int cx1 = x1 << 7;

        A0[v] = ry0 + cx0 + z0;
        A1[v] = ry1 + cx0 + z0;
        A2[v] = ry0 + cx1 + z0;
        A3[v] = ry1 + cx1 + z0;
        dzi[v] = z1 - z0;

        w000[v] = dz * dx * dy;
        w100[v] = dz * dx * ey;
        w010[v] = dz * ex * dy;
        w110[v] = dz * ex * ey;
        w001[v] = ez * dx * dy;
        w101[v] = ez * dx * ey;
        w011[v] = ez * ex * dy;
        w111[v] = ez * ex * ey;
    }

    // ---- Phase 2: issue all 16 gathers ----
    f4 c[V][8];
#pragma unroll
    for (int v = 0; v < V; ++v) {
        c[v][0] = img4[A0[v]];
        c[v][1] = img4[A1[v]];
        c[v][2] = img4[A2[v]];
        c[v][3] = img4[A3[v]];
        c[v][4] = img4[A0[v] + dzi[v]];
        c[v][5] = img4[A1[v] + dzi[v]];
        c[v][6] = img4[A2[v] + dzi[v]];
        c[v][7] = img4[A3[v] + dzi[v]];
    }

    // ---- Phase 3: weighted sum + store ----
#pragma unroll
    for (int v = 0; v < V; ++v) {
        f4 o = w000[v]*c[v][0] + w100[v]*c[v][1] + w010[v]*c[v][2] + w110[v]*c[v][3]
             + w001[v]*c[v][4] + w101[v]*c[v][5] + w011[v]*c[v][6] + w111[v]*c[v][7];

        if (idxv[v] < N) {
            __builtin_nontemporal_store(o, &out[idxv[v]]);
        }
    }
}

extern "C" void kernel_launch(void* const* d_in, const int* in_sizes, int n_in,
                              void* d_out, int out_size, void* d_ws, size_t ws_size,
                              hipStream_t stream) {
    const float* img   = (const float*)d_in[0];
    const float* trans = (const float*)d_in[1];
    f4* out = (f4*)d_out;

    int N = in_sizes[1] / 3;  // B*128^3 voxels
    const int V = 2;
    int block = 256;
    int grid = (N + block * V - 1) / (block * V);
    st3d_kernel<<<grid, block, 0, stream>>>(img, trans, out, N);
}

// Round 4
// 283.917 us; speedup vs baseline: 1.1106x; 1.1106x over previous
//
#include <hip/hip_runtime.h>

// SpatialTransformer3D: B=2, H=W=D=128, C=4.
// out[b,i,j,k,:] = trilinear sample of image[b] at c = t*grid, t in [0,1).
// KEY: sample of voxel v lies in box(center, v)  =>  octant-disjoint working
// sets of 64^3 f4 = 4.19 MB. Map octant q -> XCD q (blockIdx % 8 round-robin)
// so each XCD's gathers stay in its private 4 MB L2. trans/out are streamed
// with nontemporal hints to avoid polluting L2.

typedef float f4 __attribute__((ext_vector_type(4)));

__global__ __launch_bounds__(256) void st3d_kernel(
    const float* __restrict__ img,     // (B,128,128,128,4)
    const float* __restrict__ trans,   // (B,128,128,128,3)
    f4* __restrict__ out)              // (B,128,128,128,4) as f4
{
    // blockIdx.x in [0, 16384): q = XCD/octant, n = sequence within XCD
    int bid = blockIdx.x;
    int q   = bid & 7;                 // round-robin XCD id
    int n   = bid >> 3;                // 0..2047 per octant
    int b   = n >> 10;                 // batch (0..1)
    int m   = ((n & 1023) << 8) | threadIdx.x;   // 0..262143 within octant

    int kp = m & 63;
    int jp = (m >> 6) & 63;
    int ip = m >> 12;

    int qi = (q >> 2) & 1;
    int qj = (q >> 1) & 1;
    int qk = q & 1;

    // sweep i center-outward so the L2 working set grows from ~0
    int ipe = qi ? ip : (63 - ip);
    int i = (qi << 6) + ipe;
    int j = (qj << 6) + jp;
    int k = (qk << 6) + kp;

    int idx = (((b << 7) | i) << 14) | (j << 7) | k;   // flat voxel index

    const float step = 2.0f / 127.0f;  // jnp.linspace(-1,1,128) delta
    float gx = -1.0f + step * (float)j;
    float gy = -1.0f + step * (float)i;
    float gz = -1.0f + step * (float)k;

    const float* t = trans + (size_t)idx * 3;
    float tx = __builtin_nontemporal_load(t + 0);
    float ty = __builtin_nontemporal_load(t + 1);
    float tz = __builtin_nontemporal_load(t + 2);

    float x = (tx * gx + 1.0f) * 64.0f;
    float y = (ty * gy + 1.0f) * 64.0f;
    float z = (tz * gz + 1.0f) * 64.0f;

    int x0 = (int)floorf(x);
    int y0 = (int)floorf(y);
    int z0 = (int)floorf(z);
    int x1 = min(max(x0 + 1, 0), 127);
    int y1 = min(max(y0 + 1, 0), 127);
    int z1 = min(max(z0 + 1, 0), 127);
    x0 = min(max(x0, 0), 127);
    y0 = min(max(y0, 0), 127);
    z0 = min(max(z0, 0), 127);

    // weights use the CLIPPED upper corners (reference semantics)
    float dx = (float)x1 - x;
    float dy = (float)y1 - y;
    float dz = (float)z1 - z;
    float ex = 1.0f - dx;
    float ey = 1.0f - dy;
    float ez = 1.0f - dz;

    const f4* img4 = (const f4*)img;
    int bb  = b << 21;
    int ry0 = bb + (y0 << 14);
    int ry1 = bb + (y1 << 14);
    int cx0 = x0 << 7;
    int cx1 = x1 << 7;

    int A0 = ry0 + cx0 + z0;
    int A1 = ry1 + cx0 + z0;
    int A2 = ry0 + cx1 + z0;
    int A3 = ry1 + cx1 + z0;
    int dzi = z1 - z0;                 // 0 or 1

    f4 c000 = img4[A0];
    f4 c100 = img4[A1];
    f4 c010 = img4[A2];
    f4 c110 = img4[A3];
    f4 c001 = img4[A0 + dzi];
    f4 c101 = img4[A1 + dzi];
    f4 c011 = img4[A2 + dzi];
    f4 c111 = img4[A3 + dzi];

    float w000 = dz * dx * dy;
    float w100 = dz * dx * ey;
    float w010 = dz * ex * dy;
    float w110 = dz * ex * ey;
    float w001 = ez * dx * dy;
    float w101 = ez * dx * ey;
    float w011 = ez * ex * dy;
    float w111 = ez * ex * ey;

    f4 o = w000*c000 + w100*c100 + w010*c010 + w110*c110
         + w001*c001 + w101*c101 + w011*c011 + w111*c111;

    __builtin_nontemporal_store(o, &out[idx]);
}

extern "C" void kernel_launch(void* const* d_in, const int* in_sizes, int n_in,
                              void* d_out, int out_size, void* d_ws, size_t ws_size,
                              hipStream_t stream) {
    const float* img   = (const float*)d_in[0];
    const float* trans = (const float*)d_in[1];
    f4* out = (f4*)d_out;

    int N = in_sizes[1] / 3;           // B*128^3 = 4,194,304 voxels
    int block = 256;
    int grid = N / block;              // 16384 blocks
    st3d_kernel<<<grid, block, 0, stream>>>(img, trans, out);
}